// Round 6
// baseline (1111.375 us; speedup 1.0000x reference)
//
#include <hip/hip_runtime.h>

#define T_STEPS 1024
#define NZV 60          // valid z width
#define H 128
#define NY 8
#define NU 4
#define ZSTR 72         // padded LDS stride (shorts) for z
#define HSTR 136        // padded LDS stride (shorts) for h1/h2

typedef __attribute__((ext_vector_type(8))) short bf16x8;
typedef __attribute__((ext_vector_type(4))) short bf16x4;
typedef __attribute__((ext_vector_type(4))) float f32x4;

union U4 { unsigned u[4]; bf16x8 v; };

__device__ __forceinline__ unsigned short f2bf(float x) {
    unsigned u = __float_as_uint(x);
    u += 0x7FFFu + ((u >> 16) & 1u);
    return (unsigned short)(u >> 16);
}

// pack two f32 -> two bf16 in one u32 (RNE), single HW op
__device__ __forceinline__ unsigned cvt_pk_bf16(float lo, float hi) {
    unsigned r;
    asm("v_cvt_pk_bf16_f32 %0, %1, %2" : "=v"(r) : "v"(lo), "v"(hi));
    return r;
}

// tanh(x) = 1 - 2/(exp(2x)+1); exp2 saturates to inf/0 so no clamp needed.
__device__ __forceinline__ float tanh_fast(float x) {
    float e = __builtin_amdgcn_exp2f(x * 2.8853900817779268f);
    return fmaf(-2.0f, __builtin_amdgcn_rcpf(e + 1.0f), 1.0f);
}

#define MFMA __builtin_amdgcn_mfma_f32_16x16x32_bf16

__global__ __launch_bounds__(256, 2)
void cstr_scan_kernel(const float* __restrict__ u_g, const float* __restrict__ z0_g,
                      const float* __restrict__ W1, const float* __restrict__ b1,
                      const float* __restrict__ W2, const float* __restrict__ b2,
                      const float* __restrict__ W3, const float* __restrict__ b3,
                      float* __restrict__ out) {
    __shared__ unsigned short zbuf[2][16][ZSTR];
    __shared__ unsigned short h1s[16][HSTR];
    __shared__ unsigned short h2s[2][16][HSTR];   // double-buffered (ph = t&1 read)
    __shared__ float ybuf[32][16][NY];            // 32-deep ring of y, flushed 16/step

    const int tid   = threadIdx.x;
    const int wid   = tid >> 6;          // 0..3
    const int lane  = tid & 63;
    const int b0    = blockIdx.x * 16;   // batch row base
    const int col   = lane & 15;         // MFMA col / A row (batch row)
    const int kg    = lane >> 4;         // 0..3 (k-group)
    const int wrow0 = kg * 4;            // C-frag row base
    const int urow  = lane >> 2;         // u/z-shift row
    const int uc    = lane & 3;
    const int nbase = wid * 32;          // this wave's hidden-col base (2 n-tiles)
    const int frow  = tid >> 4;          // flush: batch row 0..15
    const int ftoff = tid & 15;          // flush: time offset 0..15

    // ---- preload weight fragments ----
    bf16x8 w1f[2][2], w2f[4][2], w3tf[4];
    float b1v[2], b2v[2];
    f32x4 b3t;
#pragma unroll
    for (int nl = 0; nl < 2; ++nl) {
        b1v[nl] = b1[nbase + nl * 16 + col];
        b2v[nl] = b2[nbase + nl * 16 + col];
    }
#pragma unroll
    for (int r = 0; r < 4; ++r) {
        int m = kg * 4 + r;
        b3t[r] = (m < NY) ? b3[m] : 0.f;    // seed for transposed GEMM3 (C'[m][b] += b3[m])
    }
#pragma unroll
    for (int kc = 0; kc < 2; ++kc)
#pragma unroll
        for (int nl = 0; nl < 2; ++nl) {
            bf16x8 v;
#pragma unroll
            for (int j = 0; j < 8; ++j) {
                int k = kc * 32 + kg * 8 + j;
                float w = (k < NZV) ? W1[k * H + nbase + nl * 16 + col] : 0.f;
                v[j] = (short)f2bf(w);
            }
            w1f[kc][nl] = v;
        }
#pragma unroll
    for (int kc = 0; kc < 4; ++kc)
#pragma unroll
        for (int nl = 0; nl < 2; ++nl) {
            bf16x8 v;
#pragma unroll
            for (int j = 0; j < 8; ++j) {
                int k = kc * 32 + kg * 8 + j;
                v[j] = (short)f2bf(W2[k * H + nbase + nl * 16 + col]);
            }
            w2f[kc][nl] = v;
        }
    // W3^T fragments: A'[m=col][k] = W3[k][m]
#pragma unroll
    for (int kc = 0; kc < 4; ++kc) {
        bf16x8 v;
#pragma unroll
        for (int j = 0; j < 8; ++j) {
            int k = kc * 32 + kg * 8 + j;
            float w = (col < NY) ? W3[k * NY + col] : 0.f;
            v[j] = (short)f2bf(w);
        }
        w3tf[kc] = v;
    }

    // ---- init z state (bf16); pads stay zero forever (slots 60..63 read by za1) ----
    {
        unsigned short* zs = &zbuf[0][0][0];
        for (int i = tid; i < 2 * 16 * ZSTR; i += 256) zs[i] = 0;
        __syncthreads();
        for (int i = tid; i < 16 * NZV; i += 256) {
            int r = i / NZV, c = i - r * NZV;
            zbuf[0][r][c] = f2bf(z0_g[(size_t)(b0 + r) * NZV + c]);
        }
        __syncthreads();
    }

    const float* uptr = u_g + (size_t)(b0 + urow) * (T_STEPS * NU) + uc;
    float ureg = 0.f, ureg_n = 0.f;
    if (wid == 3) ureg = *uptr;

    // ---- peel t = 0: GEMM1 from full z0 (no bypass), WIDE shift (copies y(-1)) ----
    {
        bf16x8 za0 = *(const bf16x8*)&zbuf[0][col][kg * 8];
        bf16x8 za1 = *(const bf16x8*)&zbuf[0][col][32 + kg * 8];
#pragma unroll
        for (int nl = 0; nl < 2; ++nl) {
            f32x4 c1 = { b1v[nl], b1v[nl], b1v[nl], b1v[nl] };
            c1 = MFMA(za0, w1f[0][nl], c1, 0, 0, 0);
            c1 = MFMA(za1, w1f[1][nl], c1, 0, 0, 0);
            unsigned p01 = cvt_pk_bf16(tanh_fast(c1[0]), tanh_fast(c1[1]));
            unsigned p23 = cvt_pk_bf16(tanh_fast(c1[2]), tanh_fast(c1[3]));
            const int n = nbase + nl * 16 + col;
            h1s[wrow0 + 0][n] = (unsigned short)p01;
            h1s[wrow0 + 1][n] = (unsigned short)(p01 >> 16);
            h1s[wrow0 + 2][n] = (unsigned short)p23;
            h1s[wrow0 + 3][n] = (unsigned short)(p23 >> 16);
        }
        if (wid == 3) {   // wide shift: slots 8..39 -> 0..31 (incl. y(-1) -> 24..31)
            bf16x4 m0 = *(const bf16x4*)&zbuf[0][urow][8 + 8 * uc];
            bf16x4 m1 = *(const bf16x4*)&zbuf[0][urow][12 + 8 * uc];
            bf16x4 m2 = *(const bf16x4*)&zbuf[0][urow][44 + 4 * uc];
            *(bf16x4*)&zbuf[1][urow][8 * uc]      = m0;
            *(bf16x4*)&zbuf[1][urow][8 * uc + 4]  = m1;
            *(bf16x4*)&zbuf[1][urow][40 + 4 * uc] = m2;
            zbuf[1][urow][56 + uc] = f2bf(ureg);
            uptr += NU;
            ureg_n = *uptr;
        }
        __syncthreads();
        bf16x8 ha0 = *(const bf16x8*)&h1s[col][0 * 32 + kg * 8];
        bf16x8 ha1 = *(const bf16x8*)&h1s[col][1 * 32 + kg * 8];
        bf16x8 ha2 = *(const bf16x8*)&h1s[col][2 * 32 + kg * 8];
        bf16x8 ha3 = *(const bf16x8*)&h1s[col][3 * 32 + kg * 8];
#pragma unroll
        for (int nl = 0; nl < 2; ++nl) {
            f32x4 a0 = { b2v[nl], b2v[nl], b2v[nl], b2v[nl] };
            f32x4 a1 = { 0.f, 0.f, 0.f, 0.f };
            a0 = MFMA(ha0, w2f[0][nl], a0, 0, 0, 0);
            a1 = MFMA(ha1, w2f[1][nl], a1, 0, 0, 0);
            a0 = MFMA(ha2, w2f[2][nl], a0, 0, 0, 0);
            a1 = MFMA(ha3, w2f[3][nl], a1, 0, 0, 0);
            f32x4 c2 = a0 + a1;
            unsigned p01 = cvt_pk_bf16(tanh_fast(c2[0]), tanh_fast(c2[1]));
            unsigned p23 = cvt_pk_bf16(tanh_fast(c2[2]), tanh_fast(c2[3]));
            const int n = nbase + nl * 16 + col;
            h2s[1][wrow0 + 0][n] = (unsigned short)p01;
            h2s[1][wrow0 + 1][n] = (unsigned short)(p01 >> 16);
            h2s[1][wrow0 + 2][n] = (unsigned short)p23;
            h2s[1][wrow0 + 3][n] = (unsigned short)(p23 >> 16);
        }
        __syncthreads();
        ureg = ureg_n;
    }

    int t = 1;

    // ---- main body: 2 barriers/step. P = t&1 (compile-time). ----
    // P_A: GEMM3'(y(t-1), all waves, from h2s[P]) + reg-bypass into za1 + GEMM1
    //      wave0 writes y->ybuf + z[nxt].24..31 ; wave3 narrow shift
    // P_B: GEMM2 -> h2s[P^1]
#define BODY(P)                                                                         \
    {                                                                                   \
        bf16x8 hp0 = *(const bf16x8*)&h2s[P][col][0 * 32 + kg * 8];                     \
        bf16x8 hp1 = *(const bf16x8*)&h2s[P][col][1 * 32 + kg * 8];                     \
        bf16x8 hp2 = *(const bf16x8*)&h2s[P][col][2 * 32 + kg * 8];                     \
        bf16x8 hp3 = *(const bf16x8*)&h2s[P][col][3 * 32 + kg * 8];                     \
        bf16x8 za0  = *(const bf16x8*)&zbuf[P][col][kg * 8];                            \
        bf16x8 za1l = *(const bf16x8*)&zbuf[P][col][32 + kg * 8];                       \
        f32x4 ya = b3t;                                                                 \
        f32x4 yb = { 0.f, 0.f, 0.f, 0.f };                                              \
        ya = MFMA(w3tf[0], hp0, ya, 0, 0, 0);                                           \
        yb = MFMA(w3tf[1], hp1, yb, 0, 0, 0);                                           \
        ya = MFMA(w3tf[2], hp2, ya, 0, 0, 0);                                           \
        yb = MFMA(w3tf[3], hp3, yb, 0, 0, 0);                                           \
        f32x4 yv = ya + yb;  /* lane(kg,b=col): y[b][kg*4+r], valid kg<2 */             \
        unsigned d0 = cvt_pk_bf16(yv[0], yv[1]);                                        \
        unsigned d1 = cvt_pk_bf16(yv[2], yv[3]);                                        \
        unsigned o0 = (unsigned)__shfl((int)d0, col + 16);                              \
        unsigned o1 = (unsigned)__shfl((int)d1, col + 16);                              \
        U4 zb_; zb_.u[0] = d0; zb_.u[1] = d1; zb_.u[2] = o0; zb_.u[3] = o1;             \
        bf16x8 za1 = (kg == 0) ? zb_.v : za1l;   /* K32..39 = y(t-1) via registers */   \
        if (wid == 0 && kg < 2) {                                                       \
            *(f32x4*)&ybuf[(t - 1) & 31][col][kg * 4] = yv;                             \
            unsigned* zp = (unsigned*)&zbuf[P ^ 1][col][24 + kg * 4];                   \
            zp[0] = d0; zp[1] = d1;          /* y(t-1) -> z(t+1).slots 24..31 */        \
        }                                                                               \
        _Pragma("unroll")                                                               \
        for (int nl = 0; nl < 2; ++nl) {                                                \
            f32x4 c1 = { b1v[nl], b1v[nl], b1v[nl], b1v[nl] };                          \
            c1 = MFMA(za0, w1f[0][nl], c1, 0, 0, 0);                                    \
            c1 = MFMA(za1, w1f[1][nl], c1, 0, 0, 0);                                    \
            unsigned p01 = cvt_pk_bf16(tanh_fast(c1[0]), tanh_fast(c1[1]));             \
            unsigned p23 = cvt_pk_bf16(tanh_fast(c1[2]), tanh_fast(c1[3]));             \
            const int n = nbase + nl * 16 + col;                                        \
            h1s[wrow0 + 0][n] = (unsigned short)p01;                                    \
            h1s[wrow0 + 1][n] = (unsigned short)(p01 >> 16);                            \
            h1s[wrow0 + 2][n] = (unsigned short)p23;                                    \
            h1s[wrow0 + 3][n] = (unsigned short)(p23 >> 16);                            \
        }                                                                               \
        if (wid == 3) {   /* narrow shift: 8..31 -> 0..23 (y-slot via direct write) */  \
            if (uc < 3) {                                                               \
                bf16x4 m0 = *(const bf16x4*)&zbuf[P][urow][8 + 8 * uc];                 \
                bf16x4 m1 = *(const bf16x4*)&zbuf[P][urow][12 + 8 * uc];                \
                *(bf16x4*)&zbuf[P ^ 1][urow][8 * uc]     = m0;                          \
                *(bf16x4*)&zbuf[P ^ 1][urow][8 * uc + 4] = m1;                          \
            }                                                                           \
            bf16x4 m2 = *(const bf16x4*)&zbuf[P][urow][44 + 4 * uc];                    \
            *(bf16x4*)&zbuf[P ^ 1][urow][40 + 4 * uc] = m2;                             \
            zbuf[P ^ 1][urow][56 + uc] = f2bf(ureg);                                    \
            uptr += NU;                                                                 \
            if (t + 1 < T_STEPS) ureg_n = *uptr;                                        \
        }                                                                               \
        __syncthreads();   /* B1 */                                                     \
        bf16x8 ha0 = *(const bf16x8*)&h1s[col][0 * 32 + kg * 8];                        \
        bf16x8 ha1 = *(const bf16x8*)&h1s[col][1 * 32 + kg * 8];                        \
        bf16x8 ha2 = *(const bf16x8*)&h1s[col][2 * 32 + kg * 8];                        \
        bf16x8 ha3 = *(const bf16x8*)&h1s[col][3 * 32 + kg * 8];                        \
        _Pragma("unroll")                                                               \
        for (int nl = 0; nl < 2; ++nl) {                                                \
            f32x4 a0 = { b2v[nl], b2v[nl], b2v[nl], b2v[nl] };                          \
            f32x4 a1 = { 0.f, 0.f, 0.f, 0.f };                                          \
            a0 = MFMA(ha0, w2f[0][nl], a0, 0, 0, 0);                                    \
            a1 = MFMA(ha1, w2f[1][nl], a1, 0, 0, 0);                                    \
            a0 = MFMA(ha2, w2f[2][nl], a0, 0, 0, 0);                                    \
            a1 = MFMA(ha3, w2f[3][nl], a1, 0, 0, 0);                                    \
            f32x4 c2 = a0 + a1;                                                         \
            unsigned p01 = cvt_pk_bf16(tanh_fast(c2[0]), tanh_fast(c2[1]));             \
            unsigned p23 = cvt_pk_bf16(tanh_fast(c2[2]), tanh_fast(c2[3]));             \
            const int n = nbase + nl * 16 + col;                                        \
            h2s[P ^ 1][wrow0 + 0][n] = (unsigned short)p01;                             \
            h2s[P ^ 1][wrow0 + 1][n] = (unsigned short)(p01 >> 16);                     \
            h2s[P ^ 1][wrow0 + 2][n] = (unsigned short)p23;                             \
            h2s[P ^ 1][wrow0 + 3][n] = (unsigned short)(p23 >> 16);                     \
        }                                                                               \
        __syncthreads();   /* B2 */                                                     \
        ureg = ureg_n;                                                                  \
        ++t;                                                                            \
    }

#pragma unroll 1
    for (int it = 0; it < 511; ++it) {
        if ((t & 15) == 1 && t > 1) {   // flush y(t-17 .. t-2): 16 slots, ring-safe
            const int bt = t - 17;
            const f32x4* yp = (const f32x4*)&ybuf[(bt & 31) + ftoff][frow][0];
            f32x4 v0 = yp[0], v1 = yp[1];
            float* op = out + ((size_t)(b0 + frow) * T_STEPS + bt + ftoff) * NY;
            *(f32x4*)op = v0;
            *(f32x4*)(op + 4) = v1;
        }
        BODY(1)
        BODY(0)
    }
    BODY(1)   // t = 1023
#undef BODY

    // ---- epilogue: y(1023) from h2s[0], then flush y(1008..1023) (slots 16..31) ----
    {
        bf16x8 hp0 = *(const bf16x8*)&h2s[0][col][0 * 32 + kg * 8];
        bf16x8 hp1 = *(const bf16x8*)&h2s[0][col][1 * 32 + kg * 8];
        bf16x8 hp2 = *(const bf16x8*)&h2s[0][col][2 * 32 + kg * 8];
        bf16x8 hp3 = *(const bf16x8*)&h2s[0][col][3 * 32 + kg * 8];
        f32x4 ya = b3t;
        f32x4 yb = { 0.f, 0.f, 0.f, 0.f };
        ya = MFMA(w3tf[0], hp0, ya, 0, 0, 0);
        yb = MFMA(w3tf[1], hp1, yb, 0, 0, 0);
        ya = MFMA(w3tf[2], hp2, ya, 0, 0, 0);
        yb = MFMA(w3tf[3], hp3, yb, 0, 0, 0);
        f32x4 yv = ya + yb;
        if (wid == 0 && kg < 2)
            *(f32x4*)&ybuf[31][col][kg * 4] = yv;
        __syncthreads();
        const f32x4* yp = (const f32x4*)&ybuf[16 + ftoff][frow][0];
        f32x4 v0 = yp[0], v1 = yp[1];
        float* op = out + ((size_t)(b0 + frow) * T_STEPS + 1008 + ftoff) * NY;
        *(f32x4*)op = v0;
        *(f32x4*)(op + 4) = v1;
    }
}

extern "C" void kernel_launch(void* const* d_in, const int* in_sizes, int n_in,
                              void* d_out, int out_size, void* d_ws, size_t ws_size,
                              hipStream_t stream) {
    (void)in_sizes; (void)n_in; (void)d_ws; (void)ws_size; (void)out_size;
    const float* u  = (const float*)d_in[0];
    const float* z0 = (const float*)d_in[1];
    const float* W1 = (const float*)d_in[2];
    const float* b1 = (const float*)d_in[3];
    const float* W2 = (const float*)d_in[4];
    const float* b2 = (const float*)d_in[5];
    const float* W3 = (const float*)d_in[6];
    const float* b3 = (const float*)d_in[7];
    float* out = (float*)d_out;

    dim3 grid(8192 / 16);   // 512 blocks x 4 waves; 16 batch rows/block
    dim3 block(256);
    cstr_scan_kernel<<<grid, block, 0, stream>>>(u, z0, W1, b1, W2, b2, W3, b3, out);
}

// Round 7
// 1084.323 us; speedup vs baseline: 1.0249x; 1.0249x over previous
//
#include <hip/hip_runtime.h>

#define T_STEPS 1024
#define NZV 60          // valid z width
#define H 128
#define NY 8
#define NU 4
#define ZSTR 72         // padded LDS stride (shorts) for z
#define HSTR 136        // padded LDS stride (shorts) for h1/h2

typedef __attribute__((ext_vector_type(8))) short bf16x8;
typedef __attribute__((ext_vector_type(4))) short bf16x4;
typedef __attribute__((ext_vector_type(4))) float f32x4;

__device__ __forceinline__ unsigned short f2bf(float x) {
    unsigned u = __float_as_uint(x);
    u += 0x7FFFu + ((u >> 16) & 1u);
    return (unsigned short)(u >> 16);
}

// pack two f32 -> two bf16 in one u32 (RNE), single HW op
__device__ __forceinline__ unsigned cvt_pk_bf16(float lo, float hi) {
    unsigned r;
    asm("v_cvt_pk_bf16_f32 %0, %1, %2" : "=v"(r) : "v"(lo), "v"(hi));
    return r;
}

// tanh(x) = 1 - 2/(exp(2x)+1); exp2 saturates to inf/0 so no clamp needed.
__device__ __forceinline__ float tanh_fast(float x) {
    float e = __builtin_amdgcn_exp2f(x * 2.8853900817779268f);
    return fmaf(-2.0f, __builtin_amdgcn_rcpf(e + 1.0f), 1.0f);
}

__global__ __launch_bounds__(256, 2)
void cstr_scan_kernel(const float* __restrict__ u_g, const float* __restrict__ z0_g,
                      const float* __restrict__ W1, const float* __restrict__ b1,
                      const float* __restrict__ W2, const float* __restrict__ b2,
                      const float* __restrict__ W3, const float* __restrict__ b3,
                      float* __restrict__ out) {
    __shared__ unsigned short zbuf[2][16][ZSTR];
    __shared__ unsigned short h1s[16][HSTR];
    __shared__ unsigned short h2s[16][HSTR];
    __shared__ float ybuf[16][16][NY];       // [t&15][row][col], flushed every 16 steps
    __shared__ float ubuf[2][16][16][NU];    // [buf][tt][row][c] u window (DMA'd)

    const int tid   = threadIdx.x;
    const int wid   = tid >> 6;          // 0..3
    const int lane  = tid & 63;
    const int b0    = blockIdx.x * 16;   // batch row base
    const int col   = lane & 15;         // MFMA col / A row
    const int kg    = lane >> 4;         // 0..3 (k-group)
    const int wrow0 = kg * 4;            // C-frag row base
    const int urow  = lane >> 2;         // u/z-shift row
    const int uc    = lane & 3;
    const int nbase = wid * 32;          // this wave's hidden-col base (2 n-tiles)

    // ---- preload weight B-fragments for this wave's 32 hidden cols ----
    bf16x8 w1f[2][2], w2f[4][2], w3f[4];
    float b1v[2], b2v[2], b3v;
#pragma unroll
    for (int nl = 0; nl < 2; ++nl) {
        b1v[nl] = b1[nbase + nl * 16 + col];
        b2v[nl] = b2[nbase + nl * 16 + col];
    }
    b3v = (col < NY) ? b3[col] : 0.f;

#pragma unroll
    for (int kc = 0; kc < 2; ++kc)
#pragma unroll
        for (int nl = 0; nl < 2; ++nl) {
            bf16x8 v;
#pragma unroll
            for (int j = 0; j < 8; ++j) {
                int k = kc * 32 + kg * 8 + j;
                float w = (k < NZV) ? W1[k * H + nbase + nl * 16 + col] : 0.f;
                v[j] = (short)f2bf(w);
            }
            w1f[kc][nl] = v;
        }
#pragma unroll
    for (int kc = 0; kc < 4; ++kc)
#pragma unroll
        for (int nl = 0; nl < 2; ++nl) {
            bf16x8 v;
#pragma unroll
            for (int j = 0; j < 8; ++j) {
                int k = kc * 32 + kg * 8 + j;
                v[j] = (short)f2bf(W2[k * H + nbase + nl * 16 + col]);
            }
            w2f[kc][nl] = v;
        }
#pragma unroll
    for (int kc = 0; kc < 4; ++kc) {
        bf16x8 v;
#pragma unroll
        for (int j = 0; j < 8; ++j) {
            int k = kc * 32 + kg * 8 + j;
            float w = (col < NY) ? W3[k * NY + col] : 0.f;
            v[j] = (short)f2bf(w);
        }
        w3f[kc] = v;
    }

    // u window DMA: 16 steps x 16 rows x 4 ch = 1024 f32 = 4 x (64 lanes x 16B).
    // LDS dest is linear (uniform base + lane*16B); mapping m=k*64+lane ->
    // [tt = k*4 + (lane>>4)][row = lane&15][c]. Issued by wave 1 only.
#define LOAD_UWIN(BI, T0)                                                              \
    if (wid == 1) {                                                                    \
        const float* usrc = u_g + (size_t)(b0 + (lane & 15)) * (T_STEPS * NU)          \
                            + (size_t)((T0) + (lane >> 4)) * NU;                       \
        _Pragma("unroll")                                                              \
        for (int k_ = 0; k_ < 4; ++k_)                                                 \
            __builtin_amdgcn_global_load_lds(                                          \
                (const __attribute__((address_space(1))) unsigned*)(usrc + k_ * 16),   \
                (__attribute__((address_space(3))) unsigned*)(&ubuf[BI][k_ * 4][0][0]),\
                16, 0, 0);                                                             \
    }

    // ---- init z state (bf16) + first u window ----
    {
        unsigned short* zs = &zbuf[0][0][0];
        for (int i = tid; i < 2 * 16 * ZSTR; i += 256) zs[i] = 0;
        __syncthreads();
        for (int i = tid; i < 16 * NZV; i += 256) {
            int r = i / NZV, c = i - r * NZV;
            zbuf[0][r][c] = f2bf(z0_g[(size_t)(b0 + r) * NZV + c]);
        }
        LOAD_UWIN(0, 0)
        __syncthreads();   // drains DMA (vmcnt) + z writes
    }

    int t = 0;

    // pipelined A-fragments of z (loaded at end of each step for the next)
    bf16x8 za0 = *(const bf16x8*)&zbuf[0][col][kg * 8];
    bf16x8 za1 = *(const bf16x8*)&zbuf[0][col][32 + kg * 8];

    // ---- one recurrence step; CUR is a compile-time 0/1 ----
#define STEP_BODY(CUR)                                                                  \
    {                                                                                   \
        const int nxt = (CUR) ^ 1;                                                      \
        /* phase 1: GEMM1 (z @ W1) on this wave's 32 cols (za pre-loaded) */            \
        _Pragma("unroll")                                                               \
        for (int nl = 0; nl < 2; ++nl) {                                                \
            f32x4 c1 = { b1v[nl], b1v[nl], b1v[nl], b1v[nl] };                          \
            c1 = __builtin_amdgcn_mfma_f32_16x16x32_bf16(za0, w1f[0][nl], c1, 0, 0, 0); \
            c1 = __builtin_amdgcn_mfma_f32_16x16x32_bf16(za1, w1f[1][nl], c1, 0, 0, 0); \
            unsigned p01 = cvt_pk_bf16(tanh_fast(c1[0]), tanh_fast(c1[1]));             \
            unsigned p23 = cvt_pk_bf16(tanh_fast(c1[2]), tanh_fast(c1[3]));             \
            const int n = nbase + nl * 16 + col;                                        \
            h1s[wrow0 + 0][n] = (unsigned short)p01;                                    \
            h1s[wrow0 + 1][n] = (unsigned short)(p01 >> 16);                            \
            h1s[wrow0 + 2][n] = (unsigned short)p23;                                    \
            h1s[wrow0 + 3][n] = (unsigned short)(p23 >> 16);                            \
        }                                                                               \
        /* wave3: z shift CUR->nxt + u insert from LDS window (y slot untouched) */     \
        if (wid == 3) {                                                                 \
            bf16x4 m0 = *(const bf16x4*)&zbuf[CUR][urow][8 + 8 * uc];                   \
            bf16x4 m1 = *(const bf16x4*)&zbuf[CUR][urow][12 + 8 * uc];                  \
            bf16x4 m2 = *(const bf16x4*)&zbuf[CUR][urow][44 + 4 * uc];                  \
            *(bf16x4*)&zbuf[nxt][urow][8 * uc]      = m0;                               \
            *(bf16x4*)&zbuf[nxt][urow][8 * uc + 4]  = m1;                               \
            *(bf16x4*)&zbuf[nxt][urow][40 + 4 * uc] = m2;                               \
            float uv = ubuf[(t >> 4) & 1][t & 15][urow][uc];                            \
            zbuf[nxt][urow][56 + uc] = f2bf(uv);                                        \
        }                                                                               \
        __syncthreads();   /* B1: h1 ready; z[nxt] (minus y) ready */                   \
        /* phase 2: GEMM2 (h1 @ W2, full K=128) */                                      \
        bf16x8 ha0 = *(const bf16x8*)&h1s[col][0 * 32 + kg * 8];                        \
        bf16x8 ha1 = *(const bf16x8*)&h1s[col][1 * 32 + kg * 8];                        \
        bf16x8 ha2 = *(const bf16x8*)&h1s[col][2 * 32 + kg * 8];                        \
        bf16x8 ha3 = *(const bf16x8*)&h1s[col][3 * 32 + kg * 8];                        \
        _Pragma("unroll")                                                               \
        for (int nl = 0; nl < 2; ++nl) {                                                \
            f32x4 a0 = { b2v[nl], b2v[nl], b2v[nl], b2v[nl] };                          \
            f32x4 a1 = { 0.f, 0.f, 0.f, 0.f };                                          \
            a0 = __builtin_amdgcn_mfma_f32_16x16x32_bf16(ha0, w2f[0][nl], a0, 0, 0, 0); \
            a1 = __builtin_amdgcn_mfma_f32_16x16x32_bf16(ha1, w2f[1][nl], a1, 0, 0, 0); \
            a0 = __builtin_amdgcn_mfma_f32_16x16x32_bf16(ha2, w2f[2][nl], a0, 0, 0, 0); \
            a1 = __builtin_amdgcn_mfma_f32_16x16x32_bf16(ha3, w2f[3][nl], a1, 0, 0, 0); \
            f32x4 c2 = a0 + a1;                                                         \
            unsigned p01 = cvt_pk_bf16(tanh_fast(c2[0]), tanh_fast(c2[1]));             \
            unsigned p23 = cvt_pk_bf16(tanh_fast(c2[2]), tanh_fast(c2[3]));             \
            const int n = nbase + nl * 16 + col;                                        \
            h2s[wrow0 + 0][n] = (unsigned short)p01;                                    \
            h2s[wrow0 + 1][n] = (unsigned short)(p01 >> 16);                            \
            h2s[wrow0 + 2][n] = (unsigned short)p23;                                    \
            h2s[wrow0 + 3][n] = (unsigned short)(p23 >> 16);                            \
        }                                                                               \
        __syncthreads();   /* B2: h2 ready */                                           \
        /* phase 3: wave0 only — GEMM3, y -> z[nxt] slot + ybuf */                      \
        if (wid == 0) {                                                                 \
            bf16x8 hp0 = *(const bf16x8*)&h2s[col][0 * 32 + kg * 8];                    \
            bf16x8 hp1 = *(const bf16x8*)&h2s[col][1 * 32 + kg * 8];                    \
            bf16x8 hp2 = *(const bf16x8*)&h2s[col][2 * 32 + kg * 8];                    \
            bf16x8 hp3 = *(const bf16x8*)&h2s[col][3 * 32 + kg * 8];                    \
            f32x4 ya = { b3v, b3v, b3v, b3v };                                          \
            f32x4 yb = { 0.f, 0.f, 0.f, 0.f };                                          \
            ya = __builtin_amdgcn_mfma_f32_16x16x32_bf16(hp0, w3f[0], ya, 0, 0, 0);     \
            yb = __builtin_amdgcn_mfma_f32_16x16x32_bf16(hp1, w3f[1], yb, 0, 0, 0);     \
            ya = __builtin_amdgcn_mfma_f32_16x16x32_bf16(hp2, w3f[2], ya, 0, 0, 0);     \
            yb = __builtin_amdgcn_mfma_f32_16x16x32_bf16(hp3, w3f[3], yb, 0, 0, 0);     \
            f32x4 y = ya + yb;                                                          \
            if (col < NY) {                                                             \
                unsigned q01 = cvt_pk_bf16(y[0], y[1]);                                 \
                unsigned q23 = cvt_pk_bf16(y[2], y[3]);                                 \
                zbuf[nxt][wrow0 + 0][32 + col] = (unsigned short)q01;                   \
                zbuf[nxt][wrow0 + 1][32 + col] = (unsigned short)(q01 >> 16);           \
                zbuf[nxt][wrow0 + 2][32 + col] = (unsigned short)q23;                   \
                zbuf[nxt][wrow0 + 3][32 + col] = (unsigned short)(q23 >> 16);           \
                const int ts = t & 15;                                                  \
                ybuf[ts][wrow0 + 0][col] = y[0];                                        \
                ybuf[ts][wrow0 + 1][col] = y[1];                                        \
                ybuf[ts][wrow0 + 2][col] = y[2];                                        \
                ybuf[ts][wrow0 + 3][col] = y[3];                                        \
            }                                                                           \
        }                                                                               \
        __syncthreads();   /* B3: z[nxt] fully valid; ybuf slot committed */            \
        /* pipeline: pre-load next step's z A-fragments */                              \
        za0 = *(const bf16x8*)&zbuf[nxt][col][kg * 8];                                  \
        za1 = *(const bf16x8*)&zbuf[nxt][col][32 + kg * 8];                             \
        ++t;                                                                            \
    }

    // coalesced ybuf flush: 16 steps x 16 rows x 8 f32; thread -> one (row,toff) pair
    const int frow  = tid >> 4;    // 0..15
    const int ftoff = tid & 15;    // 0..15

#define FLUSH(BASE_T)                                                                   \
    {                                                                                   \
        const f32x4* yp = (const f32x4*)&ybuf[ftoff][frow][0];                          \
        f32x4 v0 = yp[0], v1 = yp[1];                                                   \
        float* op = out + ((size_t)(b0 + frow) * T_STEPS + (BASE_T) + ftoff) * NY;      \
        *(f32x4*)op = v0;                                                               \
        *(f32x4*)(op + 4) = v1;                                                         \
    }

#pragma unroll 1
    for (int it = 0; it < T_STEPS / 2; ++it) {
        if ((t & 15) == 0) {
            if (t > 0)
                FLUSH(t - 16);   // reads drain at B1; slot rewrites happen after B2
            if (t + 16 < T_STEPS)
                LOAD_UWIN(((t >> 4) & 1) ^ 1, t + 16)   // lands by B1, read at t+16
        }
        STEP_BODY(0)
        STEP_BODY(1)
    }
    // final window
    FLUSH(T_STEPS - 16);
#undef STEP_BODY
#undef FLUSH
#undef LOAD_UWIN
}

extern "C" void kernel_launch(void* const* d_in, const int* in_sizes, int n_in,
                              void* d_out, int out_size, void* d_ws, size_t ws_size,
                              hipStream_t stream) {
    (void)in_sizes; (void)n_in; (void)d_ws; (void)ws_size; (void)out_size;
    const float* u  = (const float*)d_in[0];
    const float* z0 = (const float*)d_in[1];
    const float* W1 = (const float*)d_in[2];
    const float* b1 = (const float*)d_in[3];
    const float* W2 = (const float*)d_in[4];
    const float* b2 = (const float*)d_in[5];
    const float* W3 = (const float*)d_in[6];
    const float* b3 = (const float*)d_in[7];
    float* out = (float*)d_out;

    dim3 grid(8192 / 16);   // 512 blocks x 4 waves; 16 batch rows/block
    dim3 block(256);
    cstr_scan_kernel<<<grid, block, 0, stream>>>(u, z0, W1, b1, W2, b2, W3, b3, out);
}

// Round 8
// 979.036 us; speedup vs baseline: 1.1352x; 1.1075x over previous
//
#include <hip/hip_runtime.h>

#define T_STEPS 1024
#define NZV 60          // valid z width
#define H 128
#define NY 8
#define NU 4
#define ZSTR 72         // padded LDS stride (shorts) for z
#define HSTR 136        // padded LDS stride (shorts) for h1

typedef __attribute__((ext_vector_type(8))) short bf16x8;
typedef __attribute__((ext_vector_type(4))) short bf16x4;
typedef __attribute__((ext_vector_type(4))) float f32x4;
typedef __attribute__((ext_vector_type(2))) unsigned uint2v;

union U4 { unsigned u[4]; bf16x8 v; };
union U2 { unsigned u[2]; bf16x4 v; };

__device__ __forceinline__ unsigned short f2bf(float x) {
    unsigned u = __float_as_uint(x);
    u += 0x7FFFu + ((u >> 16) & 1u);
    return (unsigned short)(u >> 16);
}

__device__ __forceinline__ unsigned cvt_pk_bf16(float lo, float hi) {
    unsigned r;
    asm("v_cvt_pk_bf16_f32 %0, %1, %2" : "=v"(r) : "v"(lo), "v"(hi));
    return r;
}

// tanh(x) = 1 - 2/(exp(2x)+1); exp2 saturates so no clamp needed.
__device__ __forceinline__ float tanh_fast(float x) {
    float e = __builtin_amdgcn_exp2f(x * 2.8853900817779268f);
    return fmaf(-2.0f, __builtin_amdgcn_rcpf(e + 1.0f), 1.0f);
}

#define MFMA32 __builtin_amdgcn_mfma_f32_16x16x32_bf16

// two chained 16x16x16 bf16 MFMAs (partial GEMM3 over this wave's 32 hid cols).
// inline asm => compiler hazard recognizer blind: s_nop 1 guards VALU->MFMA src,
// s_nop 7 x2 guards MFMA D -> ds_write read.
__device__ __forceinline__ f32x4 gemm3_pair(bf16x4 a0, bf16x4 b0,
                                            bf16x4 a1, bf16x4 b1, f32x4 c) {
    asm("s_nop 1\n\t"
        "v_mfma_f32_16x16x16_bf16 %0, %1, %2, %0\n\t"
        "v_mfma_f32_16x16x16_bf16 %0, %3, %4, %0\n\t"
        "s_nop 7\n\t"
        "s_nop 7"
        : "+v"(c) : "v"(a0), "v"(b0), "v"(a1), "v"(b1));
    return c;
}

__global__ __launch_bounds__(256, 2)
void cstr_scan_kernel(const float* __restrict__ u_g, const float* __restrict__ z0_g,
                      const float* __restrict__ W1, const float* __restrict__ b1,
                      const float* __restrict__ W2, const float* __restrict__ b2,
                      const float* __restrict__ W3, const float* __restrict__ b3,
                      float* __restrict__ out) {
    __shared__ unsigned short zbuf[2][16][ZSTR];
    __shared__ unsigned short h1s[16][HSTR];
    __shared__ f32x4 ypart[4][64];           // per-wave GEMM3 partials (y^T frags)
    __shared__ float ybuf[32][16][NY];       // 32-deep y ring, flushed 16/step
    __shared__ float ubuf[2][16][16][NU];    // u windows (DMA'd)

    const int tid   = threadIdx.x;
    const int wid   = tid >> 6;          // 0..3
    const int lane  = tid & 63;
    const int b0    = blockIdx.x * 16;   // batch row base
    const int col   = lane & 15;         // batch row (all swapped C-frags)
    const int kg    = lane >> 4;         // 0..3
    const int urow  = lane >> 2;         // shift row
    const int uc    = lane & 3;
    const int nbase = wid * 32;          // this wave's hidden-col base
    const int frow  = tid >> 4;          // flush: batch row
    const int ftoff = tid & 15;          // flush: time offset

    // ---- preload weight fragments (A-operands of swapped MFMAs) ----
    bf16x8 w1f[2][2], w2f[4][2];
    bf16x4 w3a0, w3a1;
    f32x4 b1t[2], b2t[2], b3t;
#pragma unroll
    for (int nl = 0; nl < 2; ++nl)
#pragma unroll
        for (int r = 0; r < 4; ++r) {
            b1t[nl][r] = b1[nbase + nl * 16 + kg * 4 + r];
            b2t[nl][r] = b2[nbase + nl * 16 + kg * 4 + r];
        }
#pragma unroll
    for (int r = 0; r < 4; ++r) {
        int m = kg * 4 + r;
        b3t[r] = (m < NY) ? b3[m] : 0.f;
    }
#pragma unroll
    for (int kc = 0; kc < 2; ++kc)
#pragma unroll
        for (int nl = 0; nl < 2; ++nl) {
            bf16x8 v;
#pragma unroll
            for (int j = 0; j < 8; ++j) {
                int k = kc * 32 + kg * 8 + j;
                float w = (k < NZV) ? W1[k * H + nbase + nl * 16 + col] : 0.f;
                v[j] = (short)f2bf(w);
            }
            w1f[kc][nl] = v;
        }
#pragma unroll
    for (int kc = 0; kc < 4; ++kc)
#pragma unroll
        for (int nl = 0; nl < 2; ++nl) {
            bf16x8 v;
#pragma unroll
            for (int j = 0; j < 8; ++j) {
                int k = kc * 32 + kg * 8 + j;
                v[j] = (short)f2bf(W2[k * H + nbase + nl * 16 + col]);
            }
            w2f[kc][nl] = v;
        }
    {   // W3^T A-frags for 16x16x16: A[m=ny=col][k = kg*4+j local]
        bf16x4 v0, v1;
#pragma unroll
        for (int j = 0; j < 4; ++j) {
            v0[j] = (short)f2bf((col < NY) ? W3[(nbase + 0  + kg * 4 + j) * NY + col] : 0.f);
            v1[j] = (short)f2bf((col < NY) ? W3[(nbase + 16 + kg * 4 + j) * NY + col] : 0.f);
        }
        w3a0 = v0; w3a1 = v1;
    }

#define LOAD_UWIN(BI, T0)                                                              \
    if (wid == 1) {                                                                    \
        const float* usrc = u_g + (size_t)(b0 + (lane & 15)) * (T_STEPS * NU)          \
                            + (size_t)((T0) + (lane >> 4)) * NU;                       \
        _Pragma("unroll")                                                              \
        for (int k_ = 0; k_ < 4; ++k_)                                                 \
            __builtin_amdgcn_global_load_lds(                                          \
                (const __attribute__((address_space(1))) unsigned*)(usrc + k_ * 16),   \
                (__attribute__((address_space(3))) unsigned*)(&ubuf[BI][k_ * 4][0][0]),\
                16, 0, 0);                                                             \
    }

    // ---- init z state + first u window ----
    {
        unsigned short* zs = &zbuf[0][0][0];
        for (int i = tid; i < 2 * 16 * ZSTR; i += 256) zs[i] = 0;
        __syncthreads();
        for (int i = tid; i < 16 * NZV; i += 256) {
            int r = i / NZV, c = i - r * NZV;
            zbuf[0][r][c] = f2bf(z0_g[(size_t)(b0 + r) * NZV + c]);
        }
        LOAD_UWIN(0, 0)
        __syncthreads();
    }

    bf16x8 za0, za1l;
    int t = 0;

    // ---- peel t=0: real z0 y-slot (no bypass), wide shift ----
    {
        bf16x8 pza0 = *(const bf16x8*)&zbuf[0][col][kg * 8];
        bf16x8 pza1 = *(const bf16x8*)&zbuf[0][col][32 + kg * 8];
#pragma unroll
        for (int nl = 0; nl < 2; ++nl) {
            f32x4 c1 = b1t[nl];
            c1 = MFMA32(w1f[0][nl], pza0, c1, 0, 0, 0);
            c1 = MFMA32(w1f[1][nl], pza1, c1, 0, 0, 0);
            unsigned p01 = cvt_pk_bf16(tanh_fast(c1[0]), tanh_fast(c1[1]));
            unsigned p23 = cvt_pk_bf16(tanh_fast(c1[2]), tanh_fast(c1[3]));
            *(uint2v*)&h1s[col][nbase + nl * 16 + kg * 4] = uint2v{p01, p23};
        }
        if (wid == 3) {   // wide shift 8..39 -> 0..31 (moves z0's y-slot), 44..59 -> 40..55
            bf16x4 m0 = *(const bf16x4*)&zbuf[0][urow][8 + 8 * uc];
            bf16x4 m1 = *(const bf16x4*)&zbuf[0][urow][12 + 8 * uc];
            bf16x4 m2 = *(const bf16x4*)&zbuf[0][urow][44 + 4 * uc];
            *(bf16x4*)&zbuf[1][urow][8 * uc]      = m0;
            *(bf16x4*)&zbuf[1][urow][8 * uc + 4]  = m1;
            *(bf16x4*)&zbuf[1][urow][40 + 4 * uc] = m2;
            zbuf[1][urow][56 + uc] = f2bf(ubuf[0][0][urow][uc]);
        }
        __syncthreads();   // B1
        bf16x8 ha0 = *(const bf16x8*)&h1s[col][0 * 32 + kg * 8];
        bf16x8 ha1 = *(const bf16x8*)&h1s[col][1 * 32 + kg * 8];
        bf16x8 ha2 = *(const bf16x8*)&h1s[col][2 * 32 + kg * 8];
        bf16x8 ha3 = *(const bf16x8*)&h1s[col][3 * 32 + kg * 8];
        za0  = *(const bf16x8*)&zbuf[1][col][kg * 8];        // preload for t=1
        za1l = *(const bf16x8*)&zbuf[1][col][32 + kg * 8];
        bf16x4 pb0, pb1;
#pragma unroll
        for (int nl = 0; nl < 2; ++nl) {
            f32x4 a0 = b2t[nl];
            f32x4 a1 = { 0.f, 0.f, 0.f, 0.f };
            a0 = MFMA32(w2f[0][nl], ha0, a0, 0, 0, 0);
            a1 = MFMA32(w2f[1][nl], ha1, a1, 0, 0, 0);
            a0 = MFMA32(w2f[2][nl], ha2, a0, 0, 0, 0);
            a1 = MFMA32(w2f[3][nl], ha3, a1, 0, 0, 0);
            f32x4 c2 = a0 + a1;
            U2 p; p.u[0] = cvt_pk_bf16(tanh_fast(c2[0]), tanh_fast(c2[1]));
            p.u[1]       = cvt_pk_bf16(tanh_fast(c2[2]), tanh_fast(c2[3]));
            if (nl == 0) pb0 = p.v; else pb1 = p.v;
        }
        f32x4 yp = (wid == 0) ? b3t : f32x4{0.f, 0.f, 0.f, 0.f};
        yp = gemm3_pair(w3a0, pb0, w3a1, pb1, yp);
        ypart[wid][lane] = yp;
        __syncthreads();   // B2
        t = 1;
    }

    // ---- main body: 2 barriers/step; P = t&1 compile-time ----
#define BODY(P)                                                                         \
    {                                                                                   \
        /* finalize y(t-1) from partials (all waves; needed for za1 bypass) */          \
        f32x4 y_ = ypart[0][lane] + ypart[1][lane] + ypart[2][lane] + ypart[3][lane];   \
        unsigned d0 = cvt_pk_bf16(y_[0], y_[1]);                                        \
        unsigned d1 = cvt_pk_bf16(y_[2], y_[3]);                                        \
        unsigned o0 = (unsigned)__builtin_amdgcn_ds_swizzle((int)d0, 0x401F);           \
        unsigned o1 = (unsigned)__builtin_amdgcn_ds_swizzle((int)d1, 0x401F);           \
        U4 zb_; zb_.u[0] = d0; zb_.u[1] = d1; zb_.u[2] = o0; zb_.u[3] = o1;             \
        bf16x8 za1 = (kg == 0) ? zb_.v : za1l;   /* K=32..39 = y(t-1) in registers */   \
        if (wid == 1 && kg < 2) {                                                       \
            *(f32x4*)&ybuf[(t - 1) & 31][col][kg * 4] = y_;                             \
            *(uint2v*)&zbuf[(P) ^ 1][col][24 + kg * 4] = uint2v{d0, d1};                \
        }                                                                               \
        _Pragma("unroll")                                                               \
        for (int nl = 0; nl < 2; ++nl) {                                                \
            f32x4 c1 = b1t[nl];                                                         \
            c1 = MFMA32(w1f[0][nl], za0, c1, 0, 0, 0);                                  \
            c1 = MFMA32(w1f[1][nl], za1, c1, 0, 0, 0);                                  \
            unsigned p01 = cvt_pk_bf16(tanh_fast(c1[0]), tanh_fast(c1[1]));             \
            unsigned p23 = cvt_pk_bf16(tanh_fast(c1[2]), tanh_fast(c1[3]));             \
            *(uint2v*)&h1s[col][nbase + nl * 16 + kg * 4] = uint2v{p01, p23};           \
        }                                                                               \
        if (wid == 3) {   /* narrow shift 8..31 -> 0..23; 44..59 -> 40..55; u insert */ \
            if (uc < 3) {                                                               \
                bf16x4 m0 = *(const bf16x4*)&zbuf[P][urow][8 + 8 * uc];                 \
                bf16x4 m1 = *(const bf16x4*)&zbuf[P][urow][12 + 8 * uc];                \
                *(bf16x4*)&zbuf[(P) ^ 1][urow][8 * uc]     = m0;                        \
                *(bf16x4*)&zbuf[(P) ^ 1][urow][8 * uc + 4] = m1;                        \
            }                                                                           \
            bf16x4 m2 = *(const bf16x4*)&zbuf[P][urow][44 + 4 * uc];                    \
            *(bf16x4*)&zbuf[(P) ^ 1][urow][40 + 4 * uc] = m2;                           \
            zbuf[(P) ^ 1][urow][56 + uc] = f2bf(ubuf[(t >> 4) & 1][t & 15][urow][uc]);  \
        }                                                                               \
        __syncthreads();   /* B1: h1 ready; z[nxt] fully final */                       \
        bf16x8 ha0 = *(const bf16x8*)&h1s[col][0 * 32 + kg * 8];                        \
        bf16x8 ha1 = *(const bf16x8*)&h1s[col][1 * 32 + kg * 8];                        \
        bf16x8 ha2 = *(const bf16x8*)&h1s[col][2 * 32 + kg * 8];                        \
        bf16x8 ha3 = *(const bf16x8*)&h1s[col][3 * 32 + kg * 8];                        \
        za0  = *(const bf16x8*)&zbuf[(P) ^ 1][col][kg * 8];        /* preload t+1 */    \
        za1l = *(const bf16x8*)&zbuf[(P) ^ 1][col][32 + kg * 8];                        \
        bf16x4 pb0, pb1;                                                                \
        _Pragma("unroll")                                                               \
        for (int nl = 0; nl < 2; ++nl) {                                                \
            f32x4 a0 = b2t[nl];                                                         \
            f32x4 a1 = { 0.f, 0.f, 0.f, 0.f };                                          \
            a0 = MFMA32(w2f[0][nl], ha0, a0, 0, 0, 0);                                  \
            a1 = MFMA32(w2f[1][nl], ha1, a1, 0, 0, 0);                                  \
            a0 = MFMA32(w2f[2][nl], ha2, a0, 0, 0, 0);                                  \
            a1 = MFMA32(w2f[3][nl], ha3, a1, 0, 0, 0);                                  \
            f32x4 c2 = a0 + a1;                                                         \
            U2 p; p.u[0] = cvt_pk_bf16(tanh_fast(c2[0]), tanh_fast(c2[1]));             \
            p.u[1]       = cvt_pk_bf16(tanh_fast(c2[2]), tanh_fast(c2[3]));             \
            if (nl == 0) pb0 = p.v; else pb1 = p.v;                                     \
        }                                                                               \
        f32x4 yp = (wid == 0) ? b3t : f32x4{0.f, 0.f, 0.f, 0.f};                        \
        yp = gemm3_pair(w3a0, pb0, w3a1, pb1, yp);                                      \
        ypart[wid][lane] = yp;                                                          \
        __syncthreads();   /* B2: partials + next-z visible */                          \
        ++t;                                                                            \
    }

#define FLUSH(BT)                                                                       \
    {                                                                                   \
        const f32x4* yp_ = (const f32x4*)&ybuf[((BT) & 31) + ftoff][frow][0];           \
        f32x4 v0 = yp_[0], v1 = yp_[1];                                                 \
        float* op = out + ((size_t)(b0 + frow) * T_STEPS + (BT) + ftoff) * NY;          \
        *(f32x4*)op = v0;                                                               \
        *(f32x4*)(op + 4) = v1;                                                         \
    }

#pragma unroll 1
    for (int it = 0; it < 511; ++it) {
        if ((t & 15) == 1) {
            if (t > 1)
                FLUSH(t - 17)
            if (t + 15 < T_STEPS)
                LOAD_UWIN((((t + 15) >> 4) & 1), t + 15)
        }
        BODY(1)
        BODY(0)
    }
    BODY(1)   // t = 1023
#undef BODY

    // ---- epilogue: finalize y(1023), flush last window (slots 16..31) ----
    {
        f32x4 y_ = ypart[0][lane] + ypart[1][lane] + ypart[2][lane] + ypart[3][lane];
        if (wid == 1 && kg < 2)
            *(f32x4*)&ybuf[31][col][kg * 4] = y_;
        __syncthreads();
        const f32x4* yp_ = (const f32x4*)&ybuf[16 + ftoff][frow][0];
        f32x4 v0 = yp_[0], v1 = yp_[1];
        float* op = out + ((size_t)(b0 + frow) * T_STEPS + 1008 + ftoff) * NY;
        *(f32x4*)op = v0;
        *(f32x4*)(op + 4) = v1;
    }
#undef FLUSH
#undef LOAD_UWIN
}

extern "C" void kernel_launch(void* const* d_in, const int* in_sizes, int n_in,
                              void* d_out, int out_size, void* d_ws, size_t ws_size,
                              hipStream_t stream) {
    (void)in_sizes; (void)n_in; (void)d_ws; (void)ws_size; (void)out_size;
    const float* u  = (const float*)d_in[0];
    const float* z0 = (const float*)d_in[1];
    const float* W1 = (const float*)d_in[2];
    const float* b1 = (const float*)d_in[3];
    const float* W2 = (const float*)d_in[4];
    const float* b2 = (const float*)d_in[5];
    const float* W3 = (const float*)d_in[6];
    const float* b3 = (const float*)d_in[7];
    float* out = (float*)d_out;

    dim3 grid(8192 / 16);   // 512 blocks x 4 waves; 16 batch rows/block
    dim3 block(256);
    cstr_scan_kernel<<<grid, block, 0, stream>>>(u, z0, W1, b1, W2, b2, W3, b3, out);
}